// Round 20
// baseline (178.032 us; speedup 1.0000x reference)
//
#include <hip/hip_runtime.h>
#include <math.h>

#define NR 8192
#define N_OSC 28
#define TWO_PI_F 6.28318530717958647692f
#define PLANE 524288   // 8192 rows * 64 k, ushorts, per plane

typedef __attribute__((ext_vector_type(8))) short s16x8;
typedef __attribute__((ext_vector_type(16))) float f32x16;
typedef __attribute__((ext_vector_type(4))) float f32x4;

#define AS3(p) ((__attribute__((address_space(3))) void*)(p))
#define AS1C(p) ((const __attribute__((address_space(1))) void*)(p))

__device__ __forceinline__ float modpos(float x) {
    float r = fmodf(x, TWO_PI_F);
    if (r < 0.0f) r += TWO_PI_F;
    return r;
}
__device__ __forceinline__ unsigned fmono(float f) {
    unsigned u = __float_as_uint(f);
    return (u & 0x80000000u) ? ~u : (u | 0x80000000u);
}
__device__ __forceinline__ unsigned short f2bf(float f) {  // RNE f32->bf16 bits
    unsigned u = __float_as_uint(f);
    return (unsigned short)((u + 0x7FFFu + ((u >> 16) & 1u)) >> 16);
}
__device__ __forceinline__ float bf2f(unsigned short h) {
    return __uint_as_float(((unsigned)h) << 16);
}

// -------- phase encode + advance + bf16 hi/mid/lo planes + reciprocal norm --------
__global__ __launch_bounds__(256) void encode_kernel(
    const float* __restrict__ detA, const float* __restrict__ detB,
    const float* __restrict__ W1, const float* __restrict__ b1,
    const float* __restrict__ W2, const float* __restrict__ b2,
    const float* __restrict__ freq,
    unsigned short* __restrict__ tabA, unsigned short* __restrict__ tabB,
    float* __restrict__ normA, float* __restrict__ normB,
    unsigned long long* __restrict__ rowMax, unsigned long long* __restrict__ colWin)
{
    __shared__ float sW1[4 * 64];
    __shared__ float sb1[64];
    __shared__ float sW2[64 * N_OSC];
    __shared__ float sb2[N_OSC];
    __shared__ float sDelta[N_OSC];

    int t = threadIdx.x;
    for (int i = t; i < 4 * 64; i += 256) sW1[i] = W1[i];
    for (int i = t; i < 64; i += 256) sb1[i] = b1[i];
    for (int i = t; i < 64 * N_OSC; i += 256) sW2[i] = W2[i];
    for (int i = t; i < N_OSC; i += 256) {
        sb2[i] = b2[i];
        sDelta[i] = (TWO_PI_F * freq[i]) * 0.01f;
    }
    __syncthreads();

    int gid = blockIdx.x * 256 + t;
    bool isA = gid < NR;
    int row = isA ? gid : gid - NR;
    const float* det = isA ? detA : detB;
    unsigned short* tab = isA ? tabA : tabB;
    float* nrm = isA ? normA : normB;

    // fold the two tiny memsets into this kernel (16384 threads == NR*2)
    if (isA) rowMax[gid] = 0ull; else colWin[gid - NR] = 0ull;

    float4 xv = *(const float4*)(det + (size_t)row * 4);
    float x0 = xv.x, x1 = xv.y, x2 = xv.z, x3 = xv.w;

    float h[64];
#pragma unroll
    for (int j = 0; j < 64; ++j) {
        float a = x0 * sW1[0 * 64 + j];
        a += x1 * sW1[1 * 64 + j];
        a += x2 * sW1[2 * 64 + j];
        a += x3 * sW1[3 * 64 + j];
        a += sb1[j];
        h[j] = fmaxf(a, 0.0f);
    }

    float raw[N_OSC];
#pragma unroll
    for (int o = 0; o < N_OSC; ++o) raw[o] = 0.0f;
#pragma unroll
    for (int j = 0; j < 64; ++j) {
        float hj = h[j];
#pragma unroll
        for (int o = 0; o < N_OSC; ++o) raw[o] += hj * sW2[j * N_OSC + o];
    }

    int rs = row & 7;               // chunk-XOR swizzle key
    size_t rbase = (size_t)row * 64;
    float csum = 0.0f;
#pragma unroll
    for (int o = 0; o < N_OSC; ++o) {
        float p = raw[o] + sb2[o];
        p = modpos(p);
        if (isA) {
            float d = sDelta[o];
#pragma unroll
            for (int s = 0; s < 5; ++s) { p = modpos(p + d); }
        }
        float sn, cs;
        sincosf(p, &sn, &cs);
        csum += cs * cs + sn * sn;
        {
            int k = o;
            unsigned short h0 = f2bf(cs); float r1 = cs - bf2f(h0);
            unsigned short h1 = f2bf(r1); float r2 = r1 - bf2f(h1);
            unsigned short h2 = f2bf(r2);
            size_t e = rbase + ((((k >> 3) ^ rs) << 3) | (k & 7));
            tab[e] = h0; tab[PLANE + e] = h1; tab[2 * PLANE + e] = h2;
        }
        {
            int k = 28 + o;
            unsigned short h0 = f2bf(sn); float r1 = sn - bf2f(h0);
            unsigned short h1 = f2bf(r1); float r2 = r1 - bf2f(h1);
            unsigned short h2 = f2bf(r2);
            size_t e = rbase + ((((k >> 3) ^ rs) << 3) | (k & 7));
            tab[e] = h0; tab[PLANE + e] = h1; tab[2 * PLANE + e] = h2;
        }
    }
#pragma unroll
    for (int k = 56; k < 64; ++k) {
        size_t e = rbase + ((((k >> 3) ^ rs) << 3) | (k & 7));
        tab[e] = 0; tab[PLANE + e] = 0; tab[2 * PLANE + e] = 0;
    }
    nrm[row] = 1.0f / (sqrtf(csum) + 1e-6f);    // reciprocal norm
}

__device__ __forceinline__ void stage_plane(const unsigned short* __restrict__ tab,
                                            int dim0, unsigned short* dst,
                                            int w, int l)
{
#pragma unroll
    for (int i = 0; i < 4; ++i) {
        int u = w * 4 + i;
        const unsigned short* g = tab + (size_t)(dim0 + 8 * u + (l >> 3)) * 64 + (l & 7) * 8;
        __builtin_amdgcn_global_load_lds(AS1C(g), AS3(dst + u * 512), 16, 0, 0);
    }
}

// -------- sim via bf16-split MFMA; LDS-scratch epilogue with FUSED row-max --------
__global__ __launch_bounds__(256) void sim_kernel(
    const unsigned short* __restrict__ tabA, const unsigned short* __restrict__ tabB,
    const float* __restrict__ normA, const float* __restrict__ normB,
    float* __restrict__ simOut, unsigned long long* __restrict__ rowMax)
{
    __shared__ __align__(16) unsigned char smem[81920];
    unsigned short* Bsh0 = (unsigned short*)(smem);
    unsigned short* Bsh1 = (unsigned short*)(smem + 16384);
    unsigned short* Bsh2 = (unsigned short*)(smem + 32768);
    unsigned short* Ash0 = (unsigned short*)(smem + 49152);
    unsigned short* Ash1 = (unsigned short*)(smem + 65536);

    int bid = blockIdx.x;
    int swz = (bid & 7) * 512 + (bid >> 3);
    int bx = swz & 63, by = swz >> 6;
    int r0 = by * 128, c0 = bx * 128;

    int t = threadIdx.x, w = t >> 6, l = t & 63;
    int wr = w >> 1, wc = w & 1;
    int lrow = l & 31;
    int kh2 = (l >> 5) * 16;
    int sw = (lrow & 7) << 4;

    stage_plane(tabB, c0, Bsh0, w, l);
    stage_plane(tabB + PLANE, c0, Bsh1, w, l);
    stage_plane(tabB + 2 * PLANE, c0, Bsh2, w, l);
    stage_plane(tabA, r0, Ash0, w, l);
    __syncthreads();
    stage_plane(tabA + PLANE, r0, Ash1, w, l);   // A_mid in flight during phase 0

    f32x16 acc00, acc01, acc10, acc11;
#pragma unroll
    for (int r = 0; r < 16; ++r) { acc00[r] = 0.f; acc01[r] = 0.f; acc10[r] = 0.f; acc11[r] = 0.f; }

    int baA0 = (wr * 64 + lrow) * 128, baA1 = baA0 + 32 * 128;
    int baB0 = (wc * 64 + lrow) * 128, baB1 = baB0 + 32 * 128;

#define FR(arr, ba, ks) (*(const s16x8*)((const char*)(arr) + (ba) + (((ks) * 32 + kh2) ^ sw)))

    s16x8 bh0[4], bh1[4];   // B_hi fragments cached across all 3 phases (32 VGPR)

    // phase 0: A_hi x {B_hi, B_mid, B_lo}
#pragma unroll
    for (int ks = 0; ks < 4; ++ks) {
        s16x8 a0 = FR(Ash0, baA0, ks), a1 = FR(Ash0, baA1, ks);
        bh0[ks] = FR(Bsh0, baB0, ks); bh1[ks] = FR(Bsh0, baB1, ks);
        acc00 = __builtin_amdgcn_mfma_f32_32x32x16_bf16(a0, bh0[ks], acc00, 0, 0, 0);
        acc01 = __builtin_amdgcn_mfma_f32_32x32x16_bf16(a0, bh1[ks], acc01, 0, 0, 0);
        acc10 = __builtin_amdgcn_mfma_f32_32x32x16_bf16(a1, bh0[ks], acc10, 0, 0, 0);
        acc11 = __builtin_amdgcn_mfma_f32_32x32x16_bf16(a1, bh1[ks], acc11, 0, 0, 0);
        s16x8 b0 = FR(Bsh1, baB0, ks), b1 = FR(Bsh1, baB1, ks);
        acc00 = __builtin_amdgcn_mfma_f32_32x32x16_bf16(a0, b0, acc00, 0, 0, 0);
        acc01 = __builtin_amdgcn_mfma_f32_32x32x16_bf16(a0, b1, acc01, 0, 0, 0);
        acc10 = __builtin_amdgcn_mfma_f32_32x32x16_bf16(a1, b0, acc10, 0, 0, 0);
        acc11 = __builtin_amdgcn_mfma_f32_32x32x16_bf16(a1, b1, acc11, 0, 0, 0);
        b0 = FR(Bsh2, baB0, ks); b1 = FR(Bsh2, baB1, ks);
        acc00 = __builtin_amdgcn_mfma_f32_32x32x16_bf16(a0, b0, acc00, 0, 0, 0);
        acc01 = __builtin_amdgcn_mfma_f32_32x32x16_bf16(a0, b1, acc01, 0, 0, 0);
        acc10 = __builtin_amdgcn_mfma_f32_32x32x16_bf16(a1, b0, acc10, 0, 0, 0);
        acc11 = __builtin_amdgcn_mfma_f32_32x32x16_bf16(a1, b1, acc11, 0, 0, 0);
    }
    __syncthreads();
    stage_plane(tabA + 2 * PLANE, r0, Ash0, w, l);   // A_lo in flight during phase 1

    // phase 1: A_mid x {B_hi(regs), B_mid}
#pragma unroll
    for (int ks = 0; ks < 4; ++ks) {
        s16x8 a0 = FR(Ash1, baA0, ks), a1 = FR(Ash1, baA1, ks);
        acc00 = __builtin_amdgcn_mfma_f32_32x32x16_bf16(a0, bh0[ks], acc00, 0, 0, 0);
        acc01 = __builtin_amdgcn_mfma_f32_32x32x16_bf16(a0, bh1[ks], acc01, 0, 0, 0);
        acc10 = __builtin_amdgcn_mfma_f32_32x32x16_bf16(a1, bh0[ks], acc10, 0, 0, 0);
        acc11 = __builtin_amdgcn_mfma_f32_32x32x16_bf16(a1, bh1[ks], acc11, 0, 0, 0);
        s16x8 b0 = FR(Bsh1, baB0, ks), b1 = FR(Bsh1, baB1, ks);
        acc00 = __builtin_amdgcn_mfma_f32_32x32x16_bf16(a0, b0, acc00, 0, 0, 0);
        acc01 = __builtin_amdgcn_mfma_f32_32x32x16_bf16(a0, b1, acc01, 0, 0, 0);
        acc10 = __builtin_amdgcn_mfma_f32_32x32x16_bf16(a1, b0, acc10, 0, 0, 0);
        acc11 = __builtin_amdgcn_mfma_f32_32x32x16_bf16(a1, b1, acc11, 0, 0, 0);
    }
    __syncthreads();

    // phase 2: A_lo x B_hi(regs)
#pragma unroll
    for (int ks = 0; ks < 4; ++ks) {
        s16x8 a0 = FR(Ash0, baA0, ks), a1 = FR(Ash0, baA1, ks);
        acc00 = __builtin_amdgcn_mfma_f32_32x32x16_bf16(a0, bh0[ks], acc00, 0, 0, 0);
        acc01 = __builtin_amdgcn_mfma_f32_32x32x16_bf16(a0, bh1[ks], acc01, 0, 0, 0);
        acc10 = __builtin_amdgcn_mfma_f32_32x32x16_bf16(a1, bh0[ks], acc10, 0, 0, 0);
        acc11 = __builtin_amdgcn_mfma_f32_32x32x16_bf16(a1, bh1[ks], acc11, 0, 0, 0);
    }
#undef FR

    float icn0 = normB[c0 + wc * 64 + lrow];        // reciprocal norms
    float icn1 = normB[c0 + wc * 64 + 32 + lrow];

    __syncthreads();                                 // staging LDS -> scratch reuse
    float* scr = (float*)(smem + w * 17408);         // 64 rows x pitch 68 floats

#pragma unroll
    for (int r = 0; r < 16; ++r) {
        int rd0 = (r & 3) + 8 * (r >> 2) + 4 * (l >> 5);
        float irn0 = normA[r0 + wr * 64 + rd0];
        scr[rd0 * 68 + lrow]      = acc00[r] * (irn0 * icn0);
        scr[rd0 * 68 + 32 + lrow] = acc01[r] * (irn0 * icn1);
        int rd1 = rd0 + 32;
        float irn1 = normA[r0 + wr * 64 + rd1];
        scr[rd1 * 68 + lrow]      = acc10[r] * (irn1 * icn0);
        scr[rd1 * 68 + 32 + lrow] = acc11[r] * (irn1 * icn1);
    }
    // wave-private scratch: no barrier needed between write and read

    // coalesced NT stores (16 x 1KB) with FUSED row-max:
    // in iteration s, the 16 lanes of group g = l>>4 hold row (4s+g)'s 64 cols.
    int cb = c0 + wc * 64 + (l & 15) * 4;
#pragma unroll
    for (int s = 0; s < 16; ++s) {
        int lr = 4 * s + (l >> 4);
        f32x4 v = *(const f32x4*)&scr[lr * 68 + (l & 15) * 4];
        int grow = r0 + wr * 64 + lr;
        __builtin_nontemporal_store(v,
            (f32x4*)&simOut[(size_t)grow * NR + cb]);

        unsigned long long key = 0ull;
#pragma unroll
        for (int e = 0; e < 4; ++e) {
            unsigned long long kk = ((unsigned long long)fmono(v[e]) << 32)
                                  | (unsigned long long)(0xFFFFFFFFu - (unsigned)(cb + e));
            if (kk > key) key = kk;
        }
        // reduce across the 16 lanes of this group (lane bits 0..3)
#pragma unroll
        for (int d = 1; d < 16; d <<= 1) {
            unsigned lo = (unsigned)key, hi = (unsigned)(key >> 32);
            unsigned olo = __shfl_xor(lo, d, 64);
            unsigned ohi = __shfl_xor(hi, d, 64);
            unsigned long long o = ((unsigned long long)ohi << 32) | olo;
            if (o > key) key = o;
        }
        if ((l & 15) == 0) atomicMax(&rowMax[grow], key);
    }
}

// -------- per-row: init matches, claim column --------
__global__ __launch_bounds__(256) void rowwin_kernel(
    const unsigned long long* __restrict__ rowMax,
    unsigned long long* __restrict__ colWin,
    float* __restrict__ outMatches)
{
    int r = blockIdx.x * 256 + threadIdx.x;
    if (r >= NR) return;
    outMatches[r] = -1.0f;
    unsigned long long key = rowMax[r];
    unsigned m = (unsigned)(key >> 32);
    unsigned bits = (m & 0x80000000u) ? (m ^ 0x80000000u) : ~m;
    float ms = __uint_as_float(bits);
    unsigned col = 0xFFFFFFFFu - (unsigned)key;
    if (ms > 0.3f) {
        unsigned long long ck = ((unsigned long long)m << 32)
                              | (unsigned long long)(0xFFFFFFFFu - (unsigned)r);
        atomicMax(&colWin[col], ck);
    }
}

// -------- per-column: winner takes the column --------
__global__ __launch_bounds__(256) void colfin_kernel(
    const unsigned long long* __restrict__ colWin,
    float* __restrict__ outMatches)
{
    int j = blockIdx.x * 256 + threadIdx.x;
    if (j >= NR) return;
    unsigned long long w = colWin[j];
    if (w != 0ull) {
        unsigned r = 0xFFFFFFFFu - (unsigned)w;
        outMatches[r] = (float)j;
    }
}

extern "C" void kernel_launch(void* const* d_in, const int* in_sizes, int n_in,
                              void* d_out, int out_size, void* d_ws, size_t ws_size,
                              hipStream_t stream) {
    const float* detA = (const float*)d_in[0];
    const float* detB = (const float*)d_in[1];
    const float* W1   = (const float*)d_in[2];
    const float* b1   = (const float*)d_in[3];
    const float* W2   = (const float*)d_in[4];
    const float* b2   = (const float*)d_in[5];
    const float* freq = (const float*)d_in[6];
    float* out = (float*)d_out;

    char* ws = (char*)d_ws;
    unsigned short* tabA = (unsigned short*)(ws);             // 3 planes x 1 MB
    unsigned short* tabB = (unsigned short*)(ws + 3145728);   // 3 planes x 1 MB
    float* normA = (float*)(ws + 6291456);
    float* normB = (float*)(ws + 6324224);
    unsigned long long* rowMax = (unsigned long long*)(ws + 6356992);
    unsigned long long* colWin = (unsigned long long*)(ws + 6422528);

    encode_kernel<<<64, 256, 0, stream>>>(detA, detB, W1, b1, W2, b2, freq,
                                          tabA, tabB, normA, normB, rowMax, colWin);
    sim_kernel<<<4096, 256, 0, stream>>>(tabA, tabB, normA, normB, out + NR, rowMax);
    rowwin_kernel<<<NR / 256, 256, 0, stream>>>(rowMax, colWin, out);
    colfin_kernel<<<NR / 256, 256, 0, stream>>>(colWin, out);
}

// Round 21
// 124.536 us; speedup vs baseline: 1.4296x; 1.4296x over previous
//
#include <hip/hip_runtime.h>
#include <math.h>

#define NR 8192
#define N_OSC 28
#define TWO_PI_F 6.28318530717958647692f
#define PLANE 524288   // 8192 rows * 64 k, ushorts, per plane

typedef __attribute__((ext_vector_type(8))) short s16x8;
typedef __attribute__((ext_vector_type(16))) float f32x16;
typedef __attribute__((ext_vector_type(4))) float f32x4;

#define AS3(p) ((__attribute__((address_space(3))) void*)(p))
#define AS1C(p) ((const __attribute__((address_space(1))) void*)(p))

__device__ __forceinline__ float modpos(float x) {
    float r = fmodf(x, TWO_PI_F);
    if (r < 0.0f) r += TWO_PI_F;
    return r;
}
__device__ __forceinline__ unsigned fmono(float f) {
    unsigned u = __float_as_uint(f);
    return (u & 0x80000000u) ? ~u : (u | 0x80000000u);
}
__device__ __forceinline__ unsigned short f2bf(float f) {  // RNE f32->bf16 bits
    unsigned u = __float_as_uint(f);
    return (unsigned short)((u + 0x7FFFu + ((u >> 16) & 1u)) >> 16);
}
__device__ __forceinline__ float bf2f(unsigned short h) {
    return __uint_as_float(((unsigned)h) << 16);
}

// -------- phase encode + advance + bf16 hi/mid/lo planes + reciprocal norm --------
__global__ __launch_bounds__(256) void encode_kernel(
    const float* __restrict__ detA, const float* __restrict__ detB,
    const float* __restrict__ W1, const float* __restrict__ b1,
    const float* __restrict__ W2, const float* __restrict__ b2,
    const float* __restrict__ freq,
    unsigned short* __restrict__ tabA, unsigned short* __restrict__ tabB,
    float* __restrict__ normA, float* __restrict__ normB,
    unsigned long long* __restrict__ rowMax, unsigned long long* __restrict__ colWin)
{
    __shared__ float sW1[4 * 64];
    __shared__ float sb1[64];
    __shared__ float sW2[64 * N_OSC];
    __shared__ float sb2[N_OSC];
    __shared__ float sDelta[N_OSC];

    int t = threadIdx.x;
    for (int i = t; i < 4 * 64; i += 256) sW1[i] = W1[i];
    for (int i = t; i < 64; i += 256) sb1[i] = b1[i];
    for (int i = t; i < 64 * N_OSC; i += 256) sW2[i] = W2[i];
    for (int i = t; i < N_OSC; i += 256) {
        sb2[i] = b2[i];
        sDelta[i] = (TWO_PI_F * freq[i]) * 0.01f;
    }
    __syncthreads();

    int gid = blockIdx.x * 256 + t;
    bool isA = gid < NR;
    int row = isA ? gid : gid - NR;
    const float* det = isA ? detA : detB;
    unsigned short* tab = isA ? tabA : tabB;
    float* nrm = isA ? normA : normB;

    // fold the two tiny memsets into this kernel (16384 threads == NR*2)
    if (isA) rowMax[gid] = 0ull; else colWin[gid - NR] = 0ull;

    float4 xv = *(const float4*)(det + (size_t)row * 4);
    float x0 = xv.x, x1 = xv.y, x2 = xv.z, x3 = xv.w;

    float h[64];
#pragma unroll
    for (int j = 0; j < 64; ++j) {
        float a = x0 * sW1[0 * 64 + j];
        a += x1 * sW1[1 * 64 + j];
        a += x2 * sW1[2 * 64 + j];
        a += x3 * sW1[3 * 64 + j];
        a += sb1[j];
        h[j] = fmaxf(a, 0.0f);
    }

    float raw[N_OSC];
#pragma unroll
    for (int o = 0; o < N_OSC; ++o) raw[o] = 0.0f;
#pragma unroll
    for (int j = 0; j < 64; ++j) {
        float hj = h[j];
#pragma unroll
        for (int o = 0; o < N_OSC; ++o) raw[o] += hj * sW2[j * N_OSC + o];
    }

    int rs = row & 7;               // chunk-XOR swizzle key
    size_t rbase = (size_t)row * 64;
    float csum = 0.0f;
#pragma unroll
    for (int o = 0; o < N_OSC; ++o) {
        float p = raw[o] + sb2[o];
        p = modpos(p);
        if (isA) {
            float d = sDelta[o];
#pragma unroll
            for (int s = 0; s < 5; ++s) { p = modpos(p + d); }
        }
        float sn, cs;
        sincosf(p, &sn, &cs);
        csum += cs * cs + sn * sn;
        {
            int k = o;
            unsigned short h0 = f2bf(cs); float r1 = cs - bf2f(h0);
            unsigned short h1 = f2bf(r1); float r2 = r1 - bf2f(h1);
            unsigned short h2 = f2bf(r2);
            size_t e = rbase + ((((k >> 3) ^ rs) << 3) | (k & 7));
            tab[e] = h0; tab[PLANE + e] = h1; tab[2 * PLANE + e] = h2;
        }
        {
            int k = 28 + o;
            unsigned short h0 = f2bf(sn); float r1 = sn - bf2f(h0);
            unsigned short h1 = f2bf(r1); float r2 = r1 - bf2f(h1);
            unsigned short h2 = f2bf(r2);
            size_t e = rbase + ((((k >> 3) ^ rs) << 3) | (k & 7));
            tab[e] = h0; tab[PLANE + e] = h1; tab[2 * PLANE + e] = h2;
        }
    }
#pragma unroll
    for (int k = 56; k < 64; ++k) {
        size_t e = rbase + ((((k >> 3) ^ rs) << 3) | (k & 7));
        tab[e] = 0; tab[PLANE + e] = 0; tab[2 * PLANE + e] = 0;
    }
    nrm[row] = 1.0f / (sqrtf(csum) + 1e-6f);    // reciprocal norm
}

__device__ __forceinline__ void stage_plane(const unsigned short* __restrict__ tab,
                                            int dim0, unsigned short* dst,
                                            int w, int l)
{
#pragma unroll
    for (int i = 0; i < 4; ++i) {
        int u = w * 4 + i;
        const unsigned short* g = tab + (size_t)(dim0 + 8 * u + (l >> 3)) * 64 + (l & 7) * 8;
        __builtin_amdgcn_global_load_lds(AS1C(g), AS3(dst + u * 512), 16, 0, 0);
    }
}

// -------- sim via bf16-split MFMA; LDS-scratch epilogue; B_hi+B_mid reg-cached --------
__global__ __launch_bounds__(256) void sim_kernel(
    const unsigned short* __restrict__ tabA, const unsigned short* __restrict__ tabB,
    const float* __restrict__ normA, const float* __restrict__ normB,
    float* __restrict__ simOut, unsigned long long* __restrict__ rowMax)
{
    __shared__ __align__(16) unsigned char smem[81920];
    unsigned short* Bsh0 = (unsigned short*)(smem);
    unsigned short* Bsh1 = (unsigned short*)(smem + 16384);
    unsigned short* Bsh2 = (unsigned short*)(smem + 32768);
    unsigned short* Ash0 = (unsigned short*)(smem + 49152);
    unsigned short* Ash1 = (unsigned short*)(smem + 65536);

    int bid = blockIdx.x;
    int swz = (bid & 7) * 512 + (bid >> 3);
    int bx = swz & 63, by = swz >> 6;
    int r0 = by * 128, c0 = bx * 128;

    int t = threadIdx.x, w = t >> 6, l = t & 63;
    int wr = w >> 1, wc = w & 1;
    int lrow = l & 31;
    int kh2 = (l >> 5) * 16;
    int sw = (lrow & 7) << 4;

    stage_plane(tabB, c0, Bsh0, w, l);
    stage_plane(tabB + PLANE, c0, Bsh1, w, l);
    stage_plane(tabB + 2 * PLANE, c0, Bsh2, w, l);
    stage_plane(tabA, r0, Ash0, w, l);
    __syncthreads();
    stage_plane(tabA + PLANE, r0, Ash1, w, l);   // A_mid in flight during phase 0

    f32x16 acc00, acc01, acc10, acc11;
#pragma unroll
    for (int r = 0; r < 16; ++r) { acc00[r] = 0.f; acc01[r] = 0.f; acc10[r] = 0.f; acc11[r] = 0.f; }

    int baA0 = (wr * 64 + lrow) * 128, baA1 = baA0 + 32 * 128;
    int baB0 = (wc * 64 + lrow) * 128, baB1 = baB0 + 32 * 128;

#define FR(arr, ba, ks) (*(const s16x8*)((const char*)(arr) + (ba) + (((ks) * 32 + kh2) ^ sw)))

    s16x8 bh0[4], bh1[4];   // B_hi fragments cached across phases 0-2 (32 VGPR)
    s16x8 bm0[4], bm1[4];   // B_mid fragments cached across phases 0-1 (32 VGPR)

    // phase 0: A_hi x {B_hi, B_mid, B_lo}
#pragma unroll
    for (int ks = 0; ks < 4; ++ks) {
        s16x8 a0 = FR(Ash0, baA0, ks), a1 = FR(Ash0, baA1, ks);
        bh0[ks] = FR(Bsh0, baB0, ks); bh1[ks] = FR(Bsh0, baB1, ks);
        acc00 = __builtin_amdgcn_mfma_f32_32x32x16_bf16(a0, bh0[ks], acc00, 0, 0, 0);
        acc01 = __builtin_amdgcn_mfma_f32_32x32x16_bf16(a0, bh1[ks], acc01, 0, 0, 0);
        acc10 = __builtin_amdgcn_mfma_f32_32x32x16_bf16(a1, bh0[ks], acc10, 0, 0, 0);
        acc11 = __builtin_amdgcn_mfma_f32_32x32x16_bf16(a1, bh1[ks], acc11, 0, 0, 0);
        bm0[ks] = FR(Bsh1, baB0, ks); bm1[ks] = FR(Bsh1, baB1, ks);
        acc00 = __builtin_amdgcn_mfma_f32_32x32x16_bf16(a0, bm0[ks], acc00, 0, 0, 0);
        acc01 = __builtin_amdgcn_mfma_f32_32x32x16_bf16(a0, bm1[ks], acc01, 0, 0, 0);
        acc10 = __builtin_amdgcn_mfma_f32_32x32x16_bf16(a1, bm0[ks], acc10, 0, 0, 0);
        acc11 = __builtin_amdgcn_mfma_f32_32x32x16_bf16(a1, bm1[ks], acc11, 0, 0, 0);
        s16x8 b0 = FR(Bsh2, baB0, ks), b1 = FR(Bsh2, baB1, ks);
        acc00 = __builtin_amdgcn_mfma_f32_32x32x16_bf16(a0, b0, acc00, 0, 0, 0);
        acc01 = __builtin_amdgcn_mfma_f32_32x32x16_bf16(a0, b1, acc01, 0, 0, 0);
        acc10 = __builtin_amdgcn_mfma_f32_32x32x16_bf16(a1, b0, acc10, 0, 0, 0);
        acc11 = __builtin_amdgcn_mfma_f32_32x32x16_bf16(a1, b1, acc11, 0, 0, 0);
    }
    __syncthreads();
    stage_plane(tabA + 2 * PLANE, r0, Ash0, w, l);   // A_lo in flight during phase 1

    // phase 1: A_mid x {B_hi(regs), B_mid(regs)}
#pragma unroll
    for (int ks = 0; ks < 4; ++ks) {
        s16x8 a0 = FR(Ash1, baA0, ks), a1 = FR(Ash1, baA1, ks);
        acc00 = __builtin_amdgcn_mfma_f32_32x32x16_bf16(a0, bh0[ks], acc00, 0, 0, 0);
        acc01 = __builtin_amdgcn_mfma_f32_32x32x16_bf16(a0, bh1[ks], acc01, 0, 0, 0);
        acc10 = __builtin_amdgcn_mfma_f32_32x32x16_bf16(a1, bh0[ks], acc10, 0, 0, 0);
        acc11 = __builtin_amdgcn_mfma_f32_32x32x16_bf16(a1, bh1[ks], acc11, 0, 0, 0);
        acc00 = __builtin_amdgcn_mfma_f32_32x32x16_bf16(a0, bm0[ks], acc00, 0, 0, 0);
        acc01 = __builtin_amdgcn_mfma_f32_32x32x16_bf16(a0, bm1[ks], acc01, 0, 0, 0);
        acc10 = __builtin_amdgcn_mfma_f32_32x32x16_bf16(a1, bm0[ks], acc10, 0, 0, 0);
        acc11 = __builtin_amdgcn_mfma_f32_32x32x16_bf16(a1, bm1[ks], acc11, 0, 0, 0);
    }
    __syncthreads();

    // phase 2: A_lo x B_hi(regs)
#pragma unroll
    for (int ks = 0; ks < 4; ++ks) {
        s16x8 a0 = FR(Ash0, baA0, ks), a1 = FR(Ash0, baA1, ks);
        acc00 = __builtin_amdgcn_mfma_f32_32x32x16_bf16(a0, bh0[ks], acc00, 0, 0, 0);
        acc01 = __builtin_amdgcn_mfma_f32_32x32x16_bf16(a0, bh1[ks], acc01, 0, 0, 0);
        acc10 = __builtin_amdgcn_mfma_f32_32x32x16_bf16(a1, bh0[ks], acc10, 0, 0, 0);
        acc11 = __builtin_amdgcn_mfma_f32_32x32x16_bf16(a1, bh1[ks], acc11, 0, 0, 0);
    }
#undef FR

    float icn0 = normB[c0 + wc * 64 + lrow];        // reciprocal norms
    float icn1 = normB[c0 + wc * 64 + 32 + lrow];

    __syncthreads();                                 // staging LDS -> scratch reuse
    float* scr = (float*)(smem + w * 17408);         // 64 rows x pitch 68 floats

#pragma unroll
    for (int r = 0; r < 16; ++r) {
        int rd0 = (r & 3) + 8 * (r >> 2) + 4 * (l >> 5);
        float irn0 = normA[r0 + wr * 64 + rd0];
        scr[rd0 * 68 + lrow]      = acc00[r] * (irn0 * icn0);
        scr[rd0 * 68 + 32 + lrow] = acc01[r] * (irn0 * icn1);
        int rd1 = rd0 + 32;
        float irn1 = normA[r0 + wr * 64 + rd1];
        scr[rd1 * 68 + lrow]      = acc10[r] * (irn1 * icn0);
        scr[rd1 * 68 + 32 + lrow] = acc11[r] * (irn1 * icn1);
    }
    // wave-private scratch: no barrier needed between write and read

    // coalesced NT stores: 16 insts x 1KB
#pragma unroll
    for (int s = 0; s < 16; ++s) {
        int lr = 4 * s + (l >> 4);
        f32x4 v = *(const f32x4*)&scr[lr * 68 + (l & 15) * 4];
        int grow = r0 + wr * 64 + lr;
        __builtin_nontemporal_store(v,
            (f32x4*)&simOut[(size_t)grow * NR + c0 + wc * 64 + (l & 15) * 4]);
    }

    // per-lane row max: lane l owns row l of the wave tile (pure VALU scan)
    {
        const float* rp = &scr[l * 68];
        float mv = -2.0f; int mc = 0;
#pragma unroll
        for (int c4 = 0; c4 < 16; ++c4) {
            f32x4 v = *(const f32x4*)&rp[c4 * 4];
#pragma unroll
            for (int e = 0; e < 4; ++e) {
                bool g = v[e] > mv;
                mv = g ? v[e] : mv;
                mc = g ? c4 * 4 + e : mc;
            }
        }
        int grow = r0 + wr * 64 + l;
        unsigned gcol = (unsigned)(c0 + wc * 64 + mc);
        unsigned long long key = ((unsigned long long)fmono(mv) << 32)
                               | (unsigned long long)(0xFFFFFFFFu - gcol);
        atomicMax(&rowMax[grow], key);
    }
}

// -------- per-row: init matches, claim column --------
__global__ __launch_bounds__(256) void rowwin_kernel(
    const unsigned long long* __restrict__ rowMax,
    unsigned long long* __restrict__ colWin,
    float* __restrict__ outMatches)
{
    int r = blockIdx.x * 256 + threadIdx.x;
    if (r >= NR) return;
    outMatches[r] = -1.0f;
    unsigned long long key = rowMax[r];
    unsigned m = (unsigned)(key >> 32);
    unsigned bits = (m & 0x80000000u) ? (m ^ 0x80000000u) : ~m;
    float ms = __uint_as_float(bits);
    unsigned col = 0xFFFFFFFFu - (unsigned)key;
    if (ms > 0.3f) {
        unsigned long long ck = ((unsigned long long)m << 32)
                              | (unsigned long long)(0xFFFFFFFFu - (unsigned)r);
        atomicMax(&colWin[col], ck);
    }
}

// -------- per-column: winner takes the column --------
__global__ __launch_bounds__(256) void colfin_kernel(
    const unsigned long long* __restrict__ colWin,
    float* __restrict__ outMatches)
{
    int j = blockIdx.x * 256 + threadIdx.x;
    if (j >= NR) return;
    unsigned long long w = colWin[j];
    if (w != 0ull) {
        unsigned r = 0xFFFFFFFFu - (unsigned)w;
        outMatches[r] = (float)j;
    }
}

extern "C" void kernel_launch(void* const* d_in, const int* in_sizes, int n_in,
                              void* d_out, int out_size, void* d_ws, size_t ws_size,
                              hipStream_t stream) {
    const float* detA = (const float*)d_in[0];
    const float* detB = (const float*)d_in[1];
    const float* W1   = (const float*)d_in[2];
    const float* b1   = (const float*)d_in[3];
    const float* W2   = (const float*)d_in[4];
    const float* b2   = (const float*)d_in[5];
    const float* freq = (const float*)d_in[6];
    float* out = (float*)d_out;

    char* ws = (char*)d_ws;
    unsigned short* tabA = (unsigned short*)(ws);             // 3 planes x 1 MB
    unsigned short* tabB = (unsigned short*)(ws + 3145728);   // 3 planes x 1 MB
    float* normA = (float*)(ws + 6291456);
    float* normB = (float*)(ws + 6324224);
    unsigned long long* rowMax = (unsigned long long*)(ws + 6356992);
    unsigned long long* colWin = (unsigned long long*)(ws + 6422528);

    encode_kernel<<<64, 256, 0, stream>>>(detA, detB, W1, b1, W2, b2, freq,
                                          tabA, tabB, normA, normB, rowMax, colWin);
    sim_kernel<<<4096, 256, 0, stream>>>(tabA, tabB, normA, normB, out + NR, rowMax);
    rowwin_kernel<<<NR / 256, 256, 0, stream>>>(rowMax, colWin, out);
    colfin_kernel<<<NR / 256, 256, 0, stream>>>(colWin, out);
}